// Round 5
// baseline (235.263 us; speedup 1.0000x reference)
//
#include <hip/hip_runtime.h>

#define BATCH  8192
#define NFEAT  2048
#define NFIELD 8
#define NFACT  64
#define FDIM   256
#define NPAIR  36

typedef short short8v __attribute__((ext_vector_type(8)));
typedef __bf16 bf16x8 __attribute__((ext_vector_type(8)));
typedef float f32x4 __attribute__((ext_vector_type(4)));

__device__ inline unsigned short f2bf(float f) {
    unsigned int u = __float_as_uint(f);
    unsigned int r = u + 0x7FFF + ((u >> 16) & 1);   // RNE
    return (unsigned short)(r >> 16);
}
__device__ inline float bf2f(unsigned short h) {
    return __uint_as_float(((unsigned int)h) << 16);
}
__device__ inline f32x4 mfma16(bf16x8 a, bf16x8 b, f32x4 c) {
    return __builtin_amdgcn_mfma_f32_16x16x32_bf16(a, b, c, 0, 0, 0);
}

// ---------------------------------------------------------------------------
// sv[i] = ||V[i, f2f[i], :]||^2
// ---------------------------------------------------------------------------
__global__ void sv_kernel(const float* __restrict__ V, const int* __restrict__ f2f,
                          float* __restrict__ sv) {
    int i = blockIdx.x * blockDim.x + threadIdx.x;
    if (i >= NFEAT) return;
    int f = f2f[i];
    const float* vp = V + (size_t)i * (NFIELD * NFACT) + (size_t)f * NFACT;
    float s = 0.f;
#pragma unroll
    for (int l = 0; l < NFACT; l += 4) {
        float4 v = *reinterpret_cast<const float4*>(vp + l);
        s += v.x * v.x + v.y * v.y + v.z * v.z + v.w * v.w;
    }
    sv[i] = s;
}

// ---------------------------------------------------------------------------
// out[i] = b[0]  (d_out is poisoned before every call)
// ---------------------------------------------------------------------------
__global__ void init_out(const float* __restrict__ bptr, float* __restrict__ out) {
    int i = blockIdx.x * blockDim.x + threadIdx.x;
    if (i < BATCH) out[i] = bptr[0];
}

// ---------------------------------------------------------------------------
// Convert V -> bf16 hi/lo, fragment-linear layout:
//   off = ((((s*8+t)*8 + kc)*4 + ct)*64 + lane)*8
//   element = V[i = s*256 + kc*32 + (lane>>4)*8 + e][t][l = ct*16 + (lane&15)]
// ---------------------------------------------------------------------------
__global__ void convert_v(const float* __restrict__ V,
                          unsigned short* __restrict__ vh, unsigned short* __restrict__ vl) {
    const int tid = blockIdx.x * 256 + threadIdx.x;        // 0 .. 131071
    const int lane = tid & 63;
    const int ct = (tid >> 6) & 3;
    const int kc = (tid >> 8) & 7;
    const int t  = (tid >> 11) & 7;
    const int s  = tid >> 14;
    const int l  = ct * 16 + (lane & 15);
    const int i0 = s * 256 + kc * 32 + (lane >> 4) * 8;
    short8v hv, lv;
#pragma unroll
    for (int e = 0; e < 8; ++e) {
        float v = V[(size_t)(i0 + e) * (NFIELD * NFACT) + t * NFACT + l];
        unsigned short h = f2bf(v);
        hv[e] = (short)h;
        lv[e] = (short)f2bf(v - bf2f(h));
    }
    *reinterpret_cast<short8v*>(vh + (size_t)tid * 8) = hv;
    *reinterpret_cast<short8v*>(vl + (size_t)tid * 8) = lv;
}

// ---------------------------------------------------------------------------
// convert_x3: one block per (16-row tile, field). 4096 blocks, 256 threads,
// ONE barrier. Coalesced 1KB reads -> LDS -> coalesced 1KB fragment writes.
// Fuses the linear + self-quadratic terms: atomicAdd per (row, field).
// X layout:
//   off = ((((rb*8 + s)*8 + kc)*8 + rt)*64 + lane)*8
//   element = x[rb*128 + rt*16 + (lane&15)][s*256 + kc*32 + (lane>>4)*8 + e]
// ---------------------------------------------------------------------------
__global__ __launch_bounds__(256) void convert_x3(
    const float* __restrict__ x, const float* __restrict__ w,
    const float* __restrict__ sv,
    unsigned short* __restrict__ xh, unsigned short* __restrict__ xl,
    float* __restrict__ out) {
    __shared__ float tile[16][260];

    const int bid = blockIdx.x;         // 0..4095
    const int rb  = bid >> 6;           // 0..63
    const int rt  = (bid >> 3) & 7;     // 0..7
    const int s   = bid & 7;            // 0..7
    const int row0 = rb * 128 + rt * 16;

    const int tid  = threadIdx.x;
    const int lane = tid & 63;
    const int wv   = tid >> 6;          // 0..3

    const int col = s * 256 + lane * 4;
    float4 w4  = *reinterpret_cast<const float4*>(w + col);
    float4 sv4 = *reinterpret_cast<const float4*>(sv + col);

    float lq[4];
#pragma unroll
    for (int p = 0; p < 4; ++p) {
        const int r = wv * 4 + p;
        float4 v = *reinterpret_cast<const float4*>(
            x + (size_t)(row0 + r) * NFEAT + col);
        *reinterpret_cast<float4*>(&tile[r][lane * 4]) = v;
        float lin = v.x * w4.x + v.y * w4.y + v.z * w4.z + v.w * w4.w;
        float q   = v.x * v.x * sv4.x + v.y * v.y * sv4.y
                  + v.z * v.z * sv4.z + v.w * v.w * sv4.w;
        lq[p] = lin - 0.25f * q;
    }
#pragma unroll
    for (int off = 1; off < 64; off <<= 1)
#pragma unroll
        for (int p = 0; p < 4; ++p)
            lq[p] += __shfl_xor(lq[p], off, 64);
    if (lane == 0) {
#pragma unroll
        for (int p = 0; p < 4; ++p)
            atomicAdd(&out[row0 + wv * 4 + p], lq[p]);
    }

    __syncthreads();

#pragma unroll
    for (int half = 0; half < 2; ++half) {
        const int kc = half * 4 + wv;
        const int r  = lane & 15;
        const int k0 = kc * 32 + (lane >> 4) * 8;
        float4 a = *reinterpret_cast<const float4*>(&tile[r][k0]);
        float4 b = *reinterpret_cast<const float4*>(&tile[r][k0 + 4]);
        float vs[8] = {a.x, a.y, a.z, a.w, b.x, b.y, b.z, b.w};
        short8v hv, lv;
#pragma unroll
        for (int e = 0; e < 8; ++e) {
            unsigned short h = f2bf(vs[e]);
            hv[e] = (short)h;
            lv[e] = (short)f2bf(vs[e] - bf2f(h));
        }
        size_t off = ((((size_t)(rb * 8 + s) * 8 + kc) * 8 + rt) * 64 + lane) * 8;
        *reinterpret_cast<short8v*>(xh + off) = hv;
        *reinterpret_cast<short8v*>(xl + off) = lv;
    }
}

// ---------------------------------------------------------------------------
// pair_mfma4: hybrid staging.
//  - X fragments: DIRECT global->reg per wave (each fragment consumed by one
//    wave only -> LDS round-trip was pure LDS-pipe waste; r4 was LDS-bound).
//  - V fragments: LDS double-buffered (2 x 16KB), staged 1 array per wave,
//    ONE barrier per K-chunk.
//  - Split-ct wave tiling: wave owns 4 row-tiles x 2 ct -> V ds_reads halve.
//    LDS demand/CU-round (12 waves): (8 rd + 4 wr)*12*12cyc = 1728 cyc
//    < MFMA 2304 cyc -> MFMA-bound.
// 3-way bf16 split: hh + hl + lh. Tile-major XCD swizzle.
// ---------------------------------------------------------------------------
__global__ __launch_bounds__(256, 3) void pair_mfma4(
    const unsigned short* __restrict__ xh, const unsigned short* __restrict__ xl,
    const unsigned short* __restrict__ vh, const unsigned short* __restrict__ vl,
    float* __restrict__ out) {
    __shared__ unsigned short vbuf[2][4][2048];   // [dbuf][vh_A,vl_A,vh_B,vl_B]  32 KB

    const int id    = blockIdx.x;            // 0..2303
    const int local = id >> 3;               // 0..287
    const int tile  = (id & 7) * 8 + local / 36;
    int p = local % 36;
    int s = 0;
    while (p >= NFIELD - s) { p -= NFIELD - s; ++s; }
    const int t = s + p;
    const bool diag = (s == t);

    const int tid = threadIdx.x, lane = tid & 63, wid = tid >> 6;
    const int rh = wid >> 1;                 // row-tile half: rt = rh*4 + i
    const int ch = wid & 1;                  // ct half: ct = ch*2 + j

    f32x4 accA[4][2] = {};                   // [rt_i][ct_j]
    f32x4 accB[4][2] = {};

    // V staging: wave wid owns array wid (0=vh_A, 1=vl_A, 2=vh_B, 3=vl_B)
    const unsigned short* vsrc = (wid & 1) ? vl : vh;
    const int vpair = (wid < 2) ? (s * 8 + t) : (t * 8 + s);
    const bool vactive = !(diag && wid >= 2);
    const size_t vbase = (size_t)vpair * 8 * 2048 + (size_t)(lane * 8);

    const size_t xbaseS = (size_t)(tile * 8 + s) * 8 * 4096
                        + (size_t)((rh * 4) * 512 + lane * 8);
    const size_t xbaseT = (size_t)(tile * 8 + t) * 8 * 4096
                        + (size_t)((rh * 4) * 512 + lane * 8);

    // prologue: stage V chunk 0 -> buf 0
    if (vactive) {
        short8v vr[4];
#pragma unroll
        for (int i = 0; i < 4; ++i)
            vr[i] = *reinterpret_cast<const short8v*>(vsrc + vbase + i * 512);
#pragma unroll
        for (int i = 0; i < 4; ++i)
            *reinterpret_cast<short8v*>(&vbuf[0][wid][i * 512 + lane * 8]) = vr[i];
    }

    for (int kc = 0; kc < 8; ++kc) {
        const int cur = kc & 1;
        const size_t xoS = xbaseS + (size_t)kc * 4096;
        const size_t xoT = xbaseT + (size_t)kc * 4096;

        // X fragments: direct to registers (no LDS)
        bf16x8 xah[4], xal[4], xch[4], xcl[4];
#pragma unroll
        for (int i = 0; i < 4; ++i) {
            xah[i] = *reinterpret_cast<const bf16x8*>(xh + xoS + i * 512);
            xal[i] = *reinterpret_cast<const bf16x8*>(xl + xoS + i * 512);
        }
        if (!diag) {
#pragma unroll
            for (int i = 0; i < 4; ++i) {
                xch[i] = *reinterpret_cast<const bf16x8*>(xh + xoT + i * 512);
                xcl[i] = *reinterpret_cast<const bf16x8*>(xl + xoT + i * 512);
            }
        }
        // V next-chunk prefetch to regs
        short8v vn[4];
        if (kc < 7 && vactive) {
            const size_t vo = vbase + (size_t)(kc + 1) * 2048;
#pragma unroll
            for (int i = 0; i < 4; ++i)
                vn[i] = *reinterpret_cast<const short8v*>(vsrc + vo + i * 512);
        }

        __syncthreads();   // buf[cur] staged; buf[cur^1] free for writing

#pragma unroll
        for (int j = 0; j < 2; ++j) {
            const int ct = ch * 2 + j;
            bf16x8 bh = *reinterpret_cast<const bf16x8*>(&vbuf[cur][0][ct * 512 + lane * 8]);
            bf16x8 bl = *reinterpret_cast<const bf16x8*>(&vbuf[cur][1][ct * 512 + lane * 8]);
#pragma unroll
            for (int i = 0; i < 4; ++i) {
                accA[i][j] = mfma16(xah[i], bh, accA[i][j]);
                accA[i][j] = mfma16(xah[i], bl, accA[i][j]);
                accA[i][j] = mfma16(xal[i], bh, accA[i][j]);
            }
            if (!diag) {
                bf16x8 dh = *reinterpret_cast<const bf16x8*>(&vbuf[cur][2][ct * 512 + lane * 8]);
                bf16x8 dl = *reinterpret_cast<const bf16x8*>(&vbuf[cur][3][ct * 512 + lane * 8]);
#pragma unroll
                for (int i = 0; i < 4; ++i) {
                    accB[i][j] = mfma16(xch[i], dh, accB[i][j]);
                    accB[i][j] = mfma16(xch[i], dl, accB[i][j]);
                    accB[i][j] = mfma16(xcl[i], dh, accB[i][j]);
                }
            }
        }

        // write next V chunk into the other buffer (read next iter, after barrier)
        if (kc < 7 && vactive) {
#pragma unroll
            for (int i = 0; i < 4; ++i)
                *reinterpret_cast<short8v*>(&vbuf[cur ^ 1][wid][i * 512 + lane * 8]) = vn[i];
        }
    }

    // epilogue: per-row dot over this wave's 2 ct (32 l-values); the other
    // ct-half wave adds the rest via a second atomicAdd.
    const float scale = diag ? 0.25f : 0.5f;
#pragma unroll
    for (int i = 0; i < 4; ++i) {
#pragma unroll
        for (int r = 0; r < 4; ++r) {
            float v = 0.f;
#pragma unroll
            for (int j = 0; j < 2; ++j)
                v += accA[i][j][r] * (diag ? accA[i][j][r] : accB[i][j][r]);
            v += __shfl_xor(v, 1, 64);
            v += __shfl_xor(v, 2, 64);
            v += __shfl_xor(v, 4, 64);
            v += __shfl_xor(v, 8, 64);
            if ((lane & 15) == 0) {
                int row = tile * 128 + (rh * 4 + i) * 16 + (lane >> 4) * 4 + r;
                atomicAdd(&out[row], scale * v);
            }
        }
    }
}

// ===========================================================================
// Fallback fp32 path, used when ws_size is too small.
// ===========================================================================
#define BM 64
#define KC 64
#define XPAD 4

__global__ void base_kernel(const float* __restrict__ x, const float* __restrict__ bptr,
                            const float* __restrict__ w, const float* __restrict__ sv,
                            float* __restrict__ out) {
    const int row = blockIdx.x;
    const int tid = threadIdx.x;
    const float* xr = x + (size_t)row * NFEAT;
    float lin = 0.f, q = 0.f;
#pragma unroll
    for (int j = 0; j < 2; ++j) {
        int idx = j * 1024 + tid * 4;
        float4 xv = *reinterpret_cast<const float4*>(xr + idx);
        float4 wv = *reinterpret_cast<const float4*>(w + idx);
        float4 sq = *reinterpret_cast<const float4*>(sv + idx);
        lin += xv.x * wv.x + xv.y * wv.y + xv.z * wv.z + xv.w * wv.w;
        q   += xv.x * xv.x * sq.x + xv.y * xv.y * sq.y
             + xv.z * xv.z * sq.z + xv.w * xv.w * sq.w;
    }
#pragma unroll
    for (int off = 32; off >= 1; off >>= 1) {
        lin += __shfl_down(lin, off, 64);
        q   += __shfl_down(q, off, 64);
    }
    __shared__ float slin[4], sq4[4];
    const int wave = tid >> 6;
    if ((tid & 63) == 0) { slin[wave] = lin; sq4[wave] = q; }
    __syncthreads();
    if (tid == 0) {
        float L = slin[0] + slin[1] + slin[2] + slin[3];
        float Q = sq4[0] + sq4[1] + sq4[2] + sq4[3];
        out[row] = bptr[0] + L - 0.25f * Q;
    }
}

__global__ __launch_bounds__(256) void pair_kernel(const float* __restrict__ x,
                                                   const float* __restrict__ V,
                                                   float* __restrict__ out) {
    __shared__ float Xs[BM][KC + XPAD];
    __shared__ float Xt[BM][KC + XPAD];
    __shared__ float Vs[KC][NFACT];
    __shared__ float Vt[KC][NFACT];

    const int tile = blockIdx.x;
    int p = blockIdx.y;
    int s = 0;
    while (p >= NFIELD - s) { p -= NFIELD - s; ++s; }
    const int t = s + p;
    const bool diag = (s == t);

    const int tid  = threadIdx.x;
    const int lgrp = tid & 15;
    const int rgrp = tid >> 4;
    const int l0 = lgrp * 4;
    const int r0 = rgrp * 4;
    const int rowBase = tile * BM;

    float accA[4][4] = {};
    float accB[4][4] = {};

    for (int kc = 0; kc < FDIM; kc += KC) {
        __syncthreads();
#pragma unroll
        for (int it = 0; it < 4; ++it) {
            int rr = (tid >> 4) + it * 16;
            const float* gx = x + (size_t)(rowBase + rr) * NFEAT + s * FDIM + kc + (tid & 15) * 4;
            *reinterpret_cast<float4*>(&Xs[rr][(tid & 15) * 4]) =
                *reinterpret_cast<const float4*>(gx);
            if (!diag) {
                const float* gx2 = x + (size_t)(rowBase + rr) * NFEAT + t * FDIM + kc + (tid & 15) * 4;
                *reinterpret_cast<float4*>(&Xt[rr][(tid & 15) * 4]) =
                    *reinterpret_cast<const float4*>(gx2);
            }
        }
#pragma unroll
        for (int it = 0; it < 4; ++it) {
            int kk = (tid >> 4) + it * 16;
            const float* gv = V + (size_t)(s * FDIM + kc + kk) * (NFIELD * NFACT) + t * NFACT + (tid & 15) * 4;
            *reinterpret_cast<float4*>(&Vs[kk][(tid & 15) * 4]) =
                *reinterpret_cast<const float4*>(gv);
            if (!diag) {
                const float* gv2 = V + (size_t)(t * FDIM + kc + kk) * (NFIELD * NFACT) + s * NFACT + (tid & 15) * 4;
                *reinterpret_cast<float4*>(&Vt[kk][(tid & 15) * 4]) =
                    *reinterpret_cast<const float4*>(gv2);
            }
        }
        __syncthreads();

        for (int k = 0; k < KC; k += 4) {
            float xa[4][4], va[4][4];
#pragma unroll
            for (int r = 0; r < 4; ++r) {
                float4 v = *reinterpret_cast<const float4*>(&Xs[r0 + r][k]);
                xa[r][0] = v.x; xa[r][1] = v.y; xa[r][2] = v.z; xa[r][3] = v.w;
            }
#pragma unroll
            for (int kk = 0; kk < 4; ++kk) {
                float4 v = *reinterpret_cast<const float4*>(&Vs[k + kk][l0]);
                va[kk][0] = v.x; va[kk][1] = v.y; va[kk][2] = v.z; va[kk][3] = v.w;
            }
#pragma unroll
            for (int kk = 0; kk < 4; ++kk)
#pragma unroll
                for (int r = 0; r < 4; ++r)
#pragma unroll
                    for (int c = 0; c < 4; ++c)
                        accA[r][c] = fmaf(xa[r][kk], va[kk][c], accA[r][c]);

            if (!diag) {
                float xb[4][4], vb[4][4];
#pragma unroll
                for (int r = 0; r < 4; ++r) {
                    float4 v = *reinterpret_cast<const float4*>(&Xt[r0 + r][k]);
                    xb[r][0] = v.x; xb[r][1] = v.y; xb[r][2] = v.z; xb[r][3] = v.w;
                }
#pragma unroll
                for (int kk = 0; kk < 4; ++kk) {
                    float4 v = *reinterpret_cast<const float4*>(&Vt[k + kk][l0]);
                    vb[kk][0] = v.x; vb[kk][1] = v.y; vb[kk][2] = v.z; vb[kk][3] = v.w;
                }
#pragma unroll
                for (int kk = 0; kk < 4; ++kk)
#pragma unroll
                    for (int r = 0; r < 4; ++r)
#pragma unroll
                        for (int c = 0; c < 4; ++c)
                            accB[r][c] = fmaf(xb[r][kk], vb[kk][c], accB[r][c]);
            }
        }
    }

    float pr[4];
#pragma unroll
    for (int r = 0; r < 4; ++r) {
        float d = 0.f;
#pragma unroll
        for (int c = 0; c < 4; ++c)
            d += accA[r][c] * (diag ? accA[r][c] : accB[r][c]);
        pr[r] = d;
    }
#pragma unroll
    for (int off = 1; off < 16; off <<= 1) {
#pragma unroll
        for (int r = 0; r < 4; ++r)
            pr[r] += __shfl_xor(pr[r], off, 64);
    }
    if (lgrp == 0) {
        const float scale = diag ? 0.25f : 0.5f;
#pragma unroll
        for (int r = 0; r < 4; ++r)
            atomicAdd(&out[rowBase + r0 + r], scale * pr[r]);
    }
}

// ---------------------------------------------------------------------------
extern "C" void kernel_launch(void* const* d_in, const int* in_sizes, int n_in,
                              void* d_out, int out_size, void* d_ws, size_t ws_size,
                              hipStream_t stream) {
    const float* x   = (const float*)d_in[0];
    const float* b   = (const float*)d_in[1];
    const float* w   = (const float*)d_in[2];
    const float* V   = (const float*)d_in[3];
    const int*   f2f = (const int*)d_in[4];
    float* out = (float*)d_out;

    const size_t SZ_XH = 33554432;   // 8192*2048*2 B
    const size_t SZ_VH = 2097152;    // 2048*512*2 B
    const size_t NEED  = 2 * SZ_XH + 2 * SZ_VH + NFEAT * sizeof(float);

    if (ws_size >= NEED) {
        char* ws = (char*)d_ws;
        unsigned short* xhp = (unsigned short*)ws;
        unsigned short* xlp = (unsigned short*)(ws + SZ_XH);
        unsigned short* vhp = (unsigned short*)(ws + 2 * SZ_XH);
        unsigned short* vlp = (unsigned short*)(ws + 2 * SZ_XH + SZ_VH);
        float* sv = (float*)(ws + 2 * SZ_XH + 2 * SZ_VH);

        sv_kernel<<<(NFEAT + 255) / 256, 256, 0, stream>>>(V, f2f, sv);
        init_out<<<(BATCH + 255) / 256, 256, 0, stream>>>(b, out);
        convert_v<<<131072 / 256, 256, 0, stream>>>(V, vhp, vlp);
        convert_x3<<<4096, 256, 0, stream>>>(x, w, sv, xhp, xlp, out);
        pair_mfma4<<<64 * NPAIR, 256, 0, stream>>>(xhp, xlp, vhp, vlp, out);
    } else {
        float* sv = (float*)d_ws;
        sv_kernel<<<(NFEAT + 255) / 256, 256, 0, stream>>>(V, f2f, sv);
        base_kernel<<<BATCH, 256, 0, stream>>>(x, b, w, sv, out);
        dim3 grid(BATCH / BM, NPAIR);
        pair_kernel<<<grid, 256, 0, stream>>>(x, V, out);
    }
}

// Round 6
// 181.909 us; speedup vs baseline: 1.2933x; 1.2933x over previous
//
#include <hip/hip_runtime.h>

#define BATCH  8192
#define NFEAT  2048
#define NFIELD 8
#define NFACT  64
#define FDIM   256

typedef short short8v __attribute__((ext_vector_type(8)));
typedef __bf16 bf16x8 __attribute__((ext_vector_type(8)));
typedef float f32x4 __attribute__((ext_vector_type(4)));

__device__ inline unsigned short f2bf(float f) {
    unsigned int u = __float_as_uint(f);
    unsigned int r = u + 0x7FFF + ((u >> 16) & 1);   // RNE
    return (unsigned short)(r >> 16);
}
__device__ inline float bf2f(unsigned short h) {
    return __uint_as_float(((unsigned int)h) << 16);
}
__device__ inline f32x4 mfma16(bf16x8 a, bf16x8 b, f32x4 c) {
    return __builtin_amdgcn_mfma_f32_16x16x32_bf16(a, b, c, 0, 0, 0);
}

// ---------------------------------------------------------------------------
// sv[i] = ||V[i, f2f[i], :]||^2   (also used by fallback path)
// ---------------------------------------------------------------------------
__global__ void sv_kernel(const float* __restrict__ V, const int* __restrict__ f2f,
                          float* __restrict__ sv) {
    int i = blockIdx.x * blockDim.x + threadIdx.x;
    if (i >= NFEAT) return;
    int f = f2f[i];
    const float* vp = V + (size_t)i * (NFIELD * NFACT) + (size_t)f * NFACT;
    float s = 0.f;
#pragma unroll
    for (int l = 0; l < NFACT; l += 4) {
        float4 v = *reinterpret_cast<const float4*>(vp + l);
        s += v.x * v.x + v.y * v.y + v.z * v.z + v.w * v.w;
    }
    sv[i] = s;
}

// ---------------------------------------------------------------------------
// prep: fuses convert_v + init_out + sv.  512 blocks x 256 threads.
// V layout: off = ((((s*8+t)*8 + kc)*4 + ct)*64 + lane)*8
//   element = V[i = s*256 + kc*32 + (lane>>4)*8 + e][t][l = ct*16 + (lane&15)]
// ---------------------------------------------------------------------------
__global__ __launch_bounds__(256) void prep_kernel(
    const float* __restrict__ V, const int* __restrict__ f2f,
    const float* __restrict__ bptr,
    unsigned short* __restrict__ vh, unsigned short* __restrict__ vl,
    float* __restrict__ sv, float* __restrict__ out) {
    const int tid = blockIdx.x * 256 + threadIdx.x;        // 0 .. 131071
    const int lane = tid & 63;
    const int ct = (tid >> 6) & 3;
    const int kc = (tid >> 8) & 7;
    const int t  = (tid >> 11) & 7;
    const int s  = tid >> 14;
    const int l  = ct * 16 + (lane & 15);
    const int i0 = s * 256 + kc * 32 + (lane >> 4) * 8;
    short8v hv, lv;
#pragma unroll
    for (int e = 0; e < 8; ++e) {
        float v = V[(size_t)(i0 + e) * (NFIELD * NFACT) + t * NFACT + l];
        unsigned short h = f2bf(v);
        hv[e] = (short)h;
        lv[e] = (short)f2bf(v - bf2f(h));
    }
    *reinterpret_cast<short8v*>(vh + (size_t)tid * 8) = hv;
    *reinterpret_cast<short8v*>(vl + (size_t)tid * 8) = lv;

    if (tid < BATCH) out[tid] = bptr[0];

    if (tid < NFEAT) {
        int f = f2f[tid];
        const float* vp = V + (size_t)tid * (NFIELD * NFACT) + (size_t)f * NFACT;
        float ssum = 0.f;
#pragma unroll
        for (int ll = 0; ll < NFACT; ll += 4) {
            float4 v = *reinterpret_cast<const float4*>(vp + ll);
            ssum += v.x * v.x + v.y * v.y + v.z * v.z + v.w * v.w;
        }
        sv[tid] = ssum;
    }
}

// ---------------------------------------------------------------------------
// convert_x3: one block per (16-row tile, field). 4096 blocks, 256 threads.
// X layout: off = ((((rb*8 + s)*8 + kc)*8 + rt)*64 + lane)*8
//   element = x[rb*128 + rt*16 + (lane&15)][s*256 + kc*32 + (lane>>4)*8 + e]
// ---------------------------------------------------------------------------
__global__ __launch_bounds__(256) void convert_x3(
    const float* __restrict__ x, const float* __restrict__ w,
    const float* __restrict__ sv,
    unsigned short* __restrict__ xh, unsigned short* __restrict__ xl,
    float* __restrict__ out) {
    __shared__ float tile[16][260];

    const int bid = blockIdx.x;         // 0..4095
    const int rb  = bid >> 6;
    const int rt  = (bid >> 3) & 7;
    const int s   = bid & 7;
    const int row0 = rb * 128 + rt * 16;

    const int tid  = threadIdx.x;
    const int lane = tid & 63;
    const int wv   = tid >> 6;

    const int col = s * 256 + lane * 4;
    float4 w4  = *reinterpret_cast<const float4*>(w + col);
    float4 sv4 = *reinterpret_cast<const float4*>(sv + col);

    float lq[4];
#pragma unroll
    for (int p = 0; p < 4; ++p) {
        const int r = wv * 4 + p;
        float4 v = *reinterpret_cast<const float4*>(
            x + (size_t)(row0 + r) * NFEAT + col);
        *reinterpret_cast<float4*>(&tile[r][lane * 4]) = v;
        float lin = v.x * w4.x + v.y * w4.y + v.z * w4.z + v.w * w4.w;
        float q   = v.x * v.x * sv4.x + v.y * v.y * sv4.y
                  + v.z * v.z * sv4.z + v.w * v.w * sv4.w;
        lq[p] = lin - 0.25f * q;
    }
#pragma unroll
    for (int off = 1; off < 64; off <<= 1)
#pragma unroll
        for (int p = 0; p < 4; ++p)
            lq[p] += __shfl_xor(lq[p], off, 64);
    if (lane == 0) {
#pragma unroll
        for (int p = 0; p < 4; ++p)
            atomicAdd(&out[row0 + wv * 4 + p], lq[p]);
    }

    __syncthreads();

#pragma unroll
    for (int half = 0; half < 2; ++half) {
        const int kc = half * 4 + wv;
        const int r  = lane & 15;
        const int k0 = kc * 32 + (lane >> 4) * 8;
        float4 a = *reinterpret_cast<const float4*>(&tile[r][k0]);
        float4 b = *reinterpret_cast<const float4*>(&tile[r][k0 + 4]);
        float vs[8] = {a.x, a.y, a.z, a.w, b.x, b.y, b.z, b.w};
        short8v hv, lv;
#pragma unroll
        for (int e = 0; e < 8; ++e) {
            unsigned short h = f2bf(vs[e]);
            hv[e] = (short)h;
            lv[e] = (short)f2bf(vs[e] - bf2f(h));
        }
        size_t off = ((((size_t)(rb * 8 + s) * 8 + kc) * 8 + rt) * 64 + lane) * 8;
        *reinterpret_cast<short8v*>(xh + off) = hv;
        *reinterpret_cast<short8v*>(xl + off) = lv;
    }
}

// ---------------------------------------------------------------------------
// pair_off: off-diagonal pairs (s<t). 1792 blocks = 28 pairs x 64 tiles.
// Side-split wave tiling: waves 0,1 -> side A (rt 0-3 / 4-7); waves 2,3 ->
// side B. X fragments direct global->reg; V LDS double-buffered, 1 barrier
// per chunk. Epilogue: cross-side dot via LDS (aliased over vbuf).
// ---------------------------------------------------------------------------
__global__ __launch_bounds__(256) void pair_off(
    const unsigned short* __restrict__ xh, const unsigned short* __restrict__ xl,
    const unsigned short* __restrict__ vh, const unsigned short* __restrict__ vl,
    float* __restrict__ out) {
    __shared__ unsigned short vbuf[2][4][2048];   // 32 KB

    const int id    = blockIdx.x;            // 0..1791
    const int local = id >> 3;               // 0..223
    const int tile  = (id & 7) * 8 + local / 28;
    int p = local % 28;
    int s = 0;
    while (p >= 7 - s) { p -= 7 - s; ++s; }
    const int t = s + 1 + p;

    const int tid = threadIdx.x, lane = tid & 63, wid = tid >> 6;
    const int sideB  = wid >> 1;
    const int rtbase = (wid & 1) * 4;

    f32x4 acc[4][4] = {};

    const unsigned short* vsrc = (wid & 1) ? vl : vh;
    const int vpair = (wid < 2) ? (s * 8 + t) : (t * 8 + s);
    const size_t vbase = (size_t)vpair * 8 * 2048 + (size_t)(lane * 8);

    const int f = sideB ? t : s;
    const size_t xbase = ((size_t)(tile * 8 + f) * 8) * 4096
                       + (size_t)(rtbase * 512 + lane * 8);
    const int varr = sideB * 2;

    {
        short8v vr[4];
#pragma unroll
        for (int i = 0; i < 4; ++i)
            vr[i] = *reinterpret_cast<const short8v*>(vsrc + vbase + i * 512);
#pragma unroll
        for (int i = 0; i < 4; ++i)
            *reinterpret_cast<short8v*>(&vbuf[0][wid][i * 512 + lane * 8]) = vr[i];
    }

    for (int kc = 0; kc < 8; ++kc) {
        const int cur = kc & 1;
        const size_t xo = xbase + (size_t)kc * 4096;

        bf16x8 ah[4], al[4];
#pragma unroll
        for (int i = 0; i < 4; ++i) {
            ah[i] = *reinterpret_cast<const bf16x8*>(xh + xo + i * 512);
            al[i] = *reinterpret_cast<const bf16x8*>(xl + xo + i * 512);
        }
        short8v vn[4];
        if (kc < 7) {
            const size_t vo = vbase + (size_t)(kc + 1) * 2048;
#pragma unroll
            for (int i = 0; i < 4; ++i)
                vn[i] = *reinterpret_cast<const short8v*>(vsrc + vo + i * 512);
        }

        __syncthreads();

#pragma unroll
        for (int j = 0; j < 4; ++j) {
            bf16x8 bh = *reinterpret_cast<const bf16x8*>(
                &vbuf[cur][varr][j * 512 + lane * 8]);
            bf16x8 bl = *reinterpret_cast<const bf16x8*>(
                &vbuf[cur][varr + 1][j * 512 + lane * 8]);
#pragma unroll
            for (int i = 0; i < 4; ++i) {
                acc[i][j] = mfma16(ah[i], bh, acc[i][j]);
                acc[i][j] = mfma16(ah[i], bl, acc[i][j]);
                acc[i][j] = mfma16(al[i], bh, acc[i][j]);
            }
        }

        if (kc < 7) {
#pragma unroll
            for (int i = 0; i < 4; ++i)
                *reinterpret_cast<short8v*>(
                    &vbuf[cur ^ 1][wid][i * 512 + lane * 8]) = vn[i];
        }
    }

    __syncthreads();
    float* fl = reinterpret_cast<float*>(vbuf);
    if (sideB) {
        const int base = (wid - 2) * 4096;
#pragma unroll
        for (int i = 0; i < 4; ++i)
#pragma unroll
            for (int j = 0; j < 4; ++j)
                *reinterpret_cast<f32x4*>(
                    &fl[base + (i * 4 + j) * 256 + lane * 4]) = acc[i][j];
    }
    __syncthreads();
    if (!sideB) {
        const int base = wid * 4096;
#pragma unroll
        for (int i = 0; i < 4; ++i) {
            f32x4 d = {0.f, 0.f, 0.f, 0.f};
#pragma unroll
            for (int j = 0; j < 4; ++j) {
                f32x4 bv = *reinterpret_cast<const f32x4*>(
                    &fl[base + (i * 4 + j) * 256 + lane * 4]);
                d += acc[i][j] * bv;
            }
#pragma unroll
            for (int r = 0; r < 4; ++r) {
                float v = d[r];
                v += __shfl_xor(v, 1, 64);
                v += __shfl_xor(v, 2, 64);
                v += __shfl_xor(v, 4, 64);
                v += __shfl_xor(v, 8, 64);
                if ((lane & 15) == 0) {
                    int row = tile * 128 + (wid * 4 + i) * 16 + (lane >> 4) * 4 + r;
                    atomicAdd(&out[row], 0.5f * v);
                }
            }
        }
    }
}

// ---------------------------------------------------------------------------
// pair_diag: diagonal pairs. 512 blocks = 8 pairs x 64 tiles. No LDS, no
// barriers; X direct, V direct (per-pair V slice is L2-hot).
// ---------------------------------------------------------------------------
__global__ __launch_bounds__(256) void pair_diag(
    const unsigned short* __restrict__ xh, const unsigned short* __restrict__ xl,
    const unsigned short* __restrict__ vh, const unsigned short* __restrict__ vl,
    float* __restrict__ out) {
    const int id    = blockIdx.x;            // 0..511
    const int local = id >> 3;               // 0..63
    const int tile  = (id & 7) * 8 + local / 8;
    const int s     = local & 7;

    const int tid = threadIdx.x, lane = tid & 63, wid = tid >> 6;
    const int rtbase = wid * 2;

    f32x4 acc[2][4] = {};

    const size_t xbase = ((size_t)(tile * 8 + s) * 8) * 4096
                       + (size_t)(rtbase * 512 + lane * 8);
    const size_t vbase = (size_t)(s * 8 + s) * 8 * 2048 + (size_t)(lane * 8);

    for (int kc = 0; kc < 8; ++kc) {
        const size_t xo = xbase + (size_t)kc * 4096;
        const size_t vo = vbase + (size_t)kc * 2048;
        bf16x8 ah[2], al[2];
#pragma unroll
        for (int i = 0; i < 2; ++i) {
            ah[i] = *reinterpret_cast<const bf16x8*>(xh + xo + i * 512);
            al[i] = *reinterpret_cast<const bf16x8*>(xl + xo + i * 512);
        }
#pragma unroll
        for (int j = 0; j < 4; ++j) {
            bf16x8 bh = *reinterpret_cast<const bf16x8*>(vh + vo + j * 512);
            bf16x8 bl = *reinterpret_cast<const bf16x8*>(vl + vo + j * 512);
#pragma unroll
            for (int i = 0; i < 2; ++i) {
                acc[i][j] = mfma16(ah[i], bh, acc[i][j]);
                acc[i][j] = mfma16(ah[i], bl, acc[i][j]);
                acc[i][j] = mfma16(al[i], bh, acc[i][j]);
            }
        }
    }

#pragma unroll
    for (int i = 0; i < 2; ++i) {
        f32x4 d = {0.f, 0.f, 0.f, 0.f};
#pragma unroll
        for (int j = 0; j < 4; ++j)
            d += acc[i][j] * acc[i][j];
#pragma unroll
        for (int r = 0; r < 4; ++r) {
            float v = d[r];
            v += __shfl_xor(v, 1, 64);
            v += __shfl_xor(v, 2, 64);
            v += __shfl_xor(v, 4, 64);
            v += __shfl_xor(v, 8, 64);
            if ((lane & 15) == 0) {
                int row = tile * 128 + (rtbase + i) * 16 + (lane >> 4) * 4 + r;
                atomicAdd(&out[row], 0.25f * v);
            }
        }
    }
}

// ===========================================================================
// Fallback fp32 path (round-1 kernels), used when ws_size is too small.
// ===========================================================================
#define BM 64
#define KC 64
#define XPAD 4

__global__ void base_kernel(const float* __restrict__ x, const float* __restrict__ bptr,
                            const float* __restrict__ w, const float* __restrict__ sv,
                            float* __restrict__ out) {
    const int row = blockIdx.x;
    const int tid = threadIdx.x;
    const float* xr = x + (size_t)row * NFEAT;
    float lin = 0.f, q = 0.f;
#pragma unroll
    for (int j = 0; j < 2; ++j) {
        int idx = j * 1024 + tid * 4;
        float4 xv = *reinterpret_cast<const float4*>(xr + idx);
        float4 wv = *reinterpret_cast<const float4*>(w + idx);
        float4 sq = *reinterpret_cast<const float4*>(sv + idx);
        lin += xv.x * wv.x + xv.y * wv.y + xv.z * wv.z + xv.w * wv.w;
        q   += xv.x * xv.x * sq.x + xv.y * xv.y * sq.y
             + xv.z * xv.z * sq.z + xv.w * xv.w * sq.w;
    }
#pragma unroll
    for (int off = 32; off >= 1; off >>= 1) {
        lin += __shfl_down(lin, off, 64);
        q   += __shfl_down(q, off, 64);
    }
    __shared__ float slin[4], sq4[4];
    const int wave = tid >> 6;
    if ((tid & 63) == 0) { slin[wave] = lin; sq4[wave] = q; }
    __syncthreads();
    if (tid == 0) {
        float L = slin[0] + slin[1] + slin[2] + slin[3];
        float Q = sq4[0] + sq4[1] + sq4[2] + sq4[3];
        out[row] = bptr[0] + L - 0.25f * Q;
    }
}

__global__ __launch_bounds__(256) void pair_kernel(const float* __restrict__ x,
                                                   const float* __restrict__ V,
                                                   float* __restrict__ out) {
    __shared__ float Xs[BM][KC + XPAD];
    __shared__ float Xt[BM][KC + XPAD];
    __shared__ float Vs[KC][NFACT];
    __shared__ float Vt[KC][NFACT];

    const int tile = blockIdx.x;
    int p = blockIdx.y;
    int s = 0;
    while (p >= NFIELD - s) { p -= NFIELD - s; ++s; }
    const int t = s + p;
    const bool diag = (s == t);

    const int tid  = threadIdx.x;
    const int lgrp = tid & 15;
    const int rgrp = tid >> 4;
    const int l0 = lgrp * 4;
    const int r0 = rgrp * 4;
    const int rowBase = tile * BM;

    float accA[4][4] = {};
    float accB[4][4] = {};

    for (int kc = 0; kc < FDIM; kc += KC) {
        __syncthreads();
#pragma unroll
        for (int it = 0; it < 4; ++it) {
            int rr = (tid >> 4) + it * 16;
            const float* gx = x + (size_t)(rowBase + rr) * NFEAT + s * FDIM + kc + (tid & 15) * 4;
            *reinterpret_cast<float4*>(&Xs[rr][(tid & 15) * 4]) =
                *reinterpret_cast<const float4*>(gx);
            if (!diag) {
                const float* gx2 = x + (size_t)(rowBase + rr) * NFEAT + t * FDIM + kc + (tid & 15) * 4;
                *reinterpret_cast<float4*>(&Xt[rr][(tid & 15) * 4]) =
                    *reinterpret_cast<const float4*>(gx2);
            }
        }
#pragma unroll
        for (int it = 0; it < 4; ++it) {
            int kk = (tid >> 4) + it * 16;
            const float* gv = V + (size_t)(s * FDIM + kc + kk) * (NFIELD * NFACT) + t * NFACT + (tid & 15) * 4;
            *reinterpret_cast<float4*>(&Vs[kk][(tid & 15) * 4]) =
                *reinterpret_cast<const float4*>(gv);
            if (!diag) {
                const float* gv2 = V + (size_t)(t * FDIM + kc + kk) * (NFIELD * NFACT) + s * NFACT + (tid & 15) * 4;
                *reinterpret_cast<float4*>(&Vt[kk][(tid & 15) * 4]) =
                    *reinterpret_cast<const float4*>(gv2);
            }
        }
        __syncthreads();

        for (int k = 0; k < KC; k += 4) {
            float xa[4][4], va[4][4];
#pragma unroll
            for (int r = 0; r < 4; ++r) {
                float4 v = *reinterpret_cast<const float4*>(&Xs[r0 + r][k]);
                xa[r][0] = v.x; xa[r][1] = v.y; xa[r][2] = v.z; xa[r][3] = v.w;
            }
#pragma unroll
            for (int kk = 0; kk < 4; ++kk) {
                float4 v = *reinterpret_cast<const float4*>(&Vs[k + kk][l0]);
                va[kk][0] = v.x; va[kk][1] = v.y; va[kk][2] = v.z; va[kk][3] = v.w;
            }
#pragma unroll
            for (int kk = 0; kk < 4; ++kk)
#pragma unroll
                for (int r = 0; r < 4; ++r)
#pragma unroll
                    for (int c = 0; c < 4; ++c)
                        accA[r][c] = fmaf(xa[r][kk], va[kk][c], accA[r][c]);

            if (!diag) {
                float xb[4][4], vb[4][4];
#pragma unroll
                for (int r = 0; r < 4; ++r) {
                    float4 v = *reinterpret_cast<const float4*>(&Xt[r0 + r][k]);
                    xb[r][0] = v.x; xb[r][1] = v.y; xb[r][2] = v.z; xb[r][3] = v.w;
                }
#pragma unroll
                for (int kk = 0; kk < 4; ++kk) {
                    float4 v = *reinterpret_cast<const float4*>(&Vt[k + kk][l0]);
                    vb[kk][0] = v.x; vb[kk][1] = v.y; vb[kk][2] = v.z; vb[kk][3] = v.w;
                }
#pragma unroll
                for (int kk = 0; kk < 4; ++kk)
#pragma unroll
                    for (int r = 0; r < 4; ++r)
#pragma unroll
                        for (int c = 0; c < 4; ++c)
                            accB[r][c] = fmaf(xb[r][kk], vb[kk][c], accB[r][c]);
            }
        }
    }

    float pr[4];
#pragma unroll
    for (int r = 0; r < 4; ++r) {
        float d = 0.f;
#pragma unroll
        for (int c = 0; c < 4; ++c)
            d += accA[r][c] * (diag ? accA[r][c] : accB[r][c]);
        pr[r] = d;
    }
#pragma unroll
    for (int off = 1; off < 16; off <<= 1) {
#pragma unroll
        for (int r = 0; r < 4; ++r)
            pr[r] += __shfl_xor(pr[r], off, 64);
    }
    if (lgrp == 0) {
        const float scale = diag ? 0.25f : 0.5f;
#pragma unroll
        for (int r = 0; r < 4; ++r)
            atomicAdd(&out[rowBase + r0 + r], scale * pr[r]);
    }
}

// ---------------------------------------------------------------------------
extern "C" void kernel_launch(void* const* d_in, const int* in_sizes, int n_in,
                              void* d_out, int out_size, void* d_ws, size_t ws_size,
                              hipStream_t stream) {
    const float* x   = (const float*)d_in[0];
    const float* b   = (const float*)d_in[1];
    const float* w   = (const float*)d_in[2];
    const float* V   = (const float*)d_in[3];
    const int*   f2f = (const int*)d_in[4];
    float* out = (float*)d_out;

    const size_t SZ_XH = 33554432;   // 8192*2048*2 B
    const size_t SZ_VH = 2097152;    // 2048*512*2 B
    const size_t NEED  = 2 * SZ_XH + 2 * SZ_VH + NFEAT * sizeof(float);

    if (ws_size >= NEED) {
        char* ws = (char*)d_ws;
        unsigned short* xhp = (unsigned short*)ws;
        unsigned short* xlp = (unsigned short*)(ws + SZ_XH);
        unsigned short* vhp = (unsigned short*)(ws + 2 * SZ_XH);
        unsigned short* vlp = (unsigned short*)(ws + 2 * SZ_XH + SZ_VH);
        float* sv = (float*)(ws + 2 * SZ_XH + 2 * SZ_VH);

        prep_kernel<<<512, 256, 0, stream>>>(V, f2f, b, vhp, vlp, sv, out);
        convert_x3<<<4096, 256, 0, stream>>>(x, w, sv, xhp, xlp, out);
        pair_diag<<<512, 256, 0, stream>>>(xhp, xlp, vhp, vlp, out);
        pair_off<<<1792, 256, 0, stream>>>(xhp, xlp, vhp, vlp, out);
    } else {
        float* sv = (float*)d_ws;
        sv_kernel<<<(NFEAT + 255) / 256, 256, 0, stream>>>(V, f2f, sv);
        base_kernel<<<BATCH, 256, 0, stream>>>(x, b, w, sv, out);
        dim3 grid(BATCH / BM, 36);
        pair_kernel<<<grid, 256, 0, stream>>>(x, V, out);
    }
}